// Round 9
// baseline (417.194 us; speedup 1.0000x reference)
//
#include <hip/hip_runtime.h>
#include <hip/hip_bf16.h>
#include <math.h>

#define DIM   2048
#define NH    16
#define HD    128
#define SEQ   2048
#define BATCH 2
#define QKVN  6144   // 3*DIM

typedef __attribute__((ext_vector_type(8))) short short8;
typedef __attribute__((ext_vector_type(4))) float f32x4;
typedef __attribute__((ext_vector_type(4))) unsigned int u32x4;
typedef __attribute__((ext_vector_type(4))) _Float16 half4;

static __device__ __forceinline__ unsigned short f2bf(float f) {
    __hip_bfloat16 h = __float2bfloat16(f);
    return *reinterpret_cast<unsigned short*>(&h);
}

// async global->LDS, 16B per lane; LDS dest = base + lane*16 (wave-uniform base)
static __device__ __forceinline__ void gload16(const void* g, void* l) {
    __builtin_amdgcn_global_load_lds(
        (const __attribute__((address_space(1))) void*)(g),
        (__attribute__((address_space(3))) void*)(l), 16, 0, 0);
}

__device__ __forceinline__ void storeC_helper(float* C, size_t idx, float v) { C[idx] = v; }
__device__ __forceinline__ void storeC_helper(__hip_bfloat16* C, size_t idx, float v) { C[idx] = __float2bfloat16(v); }

// ---------------- fused cast fp32 -> bf16 (x + 4 weights, one launch) ----------------
__global__ __launch_bounds__(256) void cast_all(const float* __restrict__ x,
                                                const float* __restrict__ wq,
                                                const float* __restrict__ wk,
                                                const float* __restrict__ wv,
                                                const float* __restrict__ wo,
                                                __hip_bfloat16* __restrict__ xb,
                                                __hip_bfloat16* __restrict__ wqkvb,
                                                __hip_bfloat16* __restrict__ wob) {
    const int VX = (BATCH * SEQ * DIM) / 4;
    const int VW = (DIM * DIM) / 4;
    int v = blockIdx.x * blockDim.x + threadIdx.x;
    const float* src; __hip_bfloat16* dst; int off;
    if (v < VX)               { src = x;  dst = xb;                            off = v; }
    else if (v < VX + VW)     { src = wq; dst = wqkvb;                         off = v - VX; }
    else if (v < VX + 2 * VW) { src = wk; dst = wqkvb + (size_t)DIM * DIM;     off = v - VX - VW; }
    else if (v < VX + 3 * VW) { src = wv; dst = wqkvb + 2ull * DIM * DIM;      off = v - VX - 2 * VW; }
    else                      { src = wo; dst = wob;                           off = v - VX - 3 * VW; }
    float4 f = *(const float4*)(src + (size_t)off * 4);
    union { unsigned short u[4]; uint2 d; } pk;
    pk.u[0] = f2bf(f.x); pk.u[1] = f2bf(f.y); pk.u[2] = f2bf(f.z); pk.u[3] = f2bf(f.w);
    *(uint2*)(dst + (size_t)off * 4) = pk.d;
}

// ---------------- bf16 GEMM, C[m,n] = sum_k A[m,k]*B[n,k] ----------------
// MODE 0: plain store to C.  MODE 1: QKV-fused — n<4096: RoPE + bf16 store;
// n>=4096: V tile transposed via LDS, stored f16 to vt[bh][d][s].
// NOTE r6: XCD-chunked swizzle REVERTED — it gave each XCD all 48 B-panels
// (25MB through a 4MB L2): FETCH 107->330MB. Default round-robin is better here.
template <int MODE, typename OutT>
__global__ __launch_bounds__(256) void gemm_bt(const __hip_bfloat16* __restrict__ A,
                                               const __hip_bfloat16* __restrict__ B,
                                               OutT* __restrict__ C,
                                               _Float16* __restrict__ vt,
                                               int M, int N, int K) {
    constexpr int BK = 64;
    __shared__ __align__(16) __hip_bfloat16 As[128 * BK];
    __shared__ __align__(16) __hip_bfloat16 Bs[128 * BK];
    int tid  = threadIdx.x;
    int lane = tid & 63;
    int wave = tid >> 6;
    int quad = lane >> 4;
    int l15  = lane & 15;
    int wr   = wave >> 1, wc = wave & 1;
    int m0 = blockIdx.y * 128;
    int n0 = blockIdx.x * 128;
    f32x4 acc[4][4] = {};

    for (int k0 = 0; k0 < K; k0 += BK) {
        __syncthreads();
#pragma unroll
        for (int c = 0; c < 4; c++) {
            int br = (wave * 4 + c) * 8;
            int r  = br + (lane >> 3);
            int cc = (lane & 7) ^ (r & 7);
            gload16(A + (size_t)(m0 + r) * K + k0 + cc * 8, As + br * 64);
            gload16(B + (size_t)(n0 + r) * K + k0 + cc * 8, Bs + br * 64);
        }
        __syncthreads();
#pragma unroll
        for (int kk = 0; kk < BK; kk += 32) {
            short8 af[4], bf4[4];
#pragma unroll
            for (int t = 0; t < 4; t++) {
                int Ra = wr * 64 + t * 16 + l15;
                int pa = ((kk >> 3) + quad) ^ (Ra & 7);
                af[t] = *(const short8*)(As + Ra * 64 + pa * 8);
                int Rb = wc * 64 + t * 16 + l15;
                int pb = ((kk >> 3) + quad) ^ (Rb & 7);
                bf4[t] = *(const short8*)(Bs + Rb * 64 + pb * 8);
            }
#pragma unroll
            for (int mt = 0; mt < 4; mt++)
#pragma unroll
                for (int nt = 0; nt < 4; nt++)
                    acc[mt][nt] = __builtin_amdgcn_mfma_f32_16x16x32_bf16(af[mt], bf4[nt], acc[mt][nt], 0, 0, 0);
        }
    }

    if (MODE == 1 && n0 >= 4096) {
        // ---- V branch: transpose 64x64 wave quadrant via LDS, store f16 ----
        __syncthreads();   // all waves done reading As/Bs
        _Float16* T = ((wave < 2) ? (_Float16*)As : (_Float16*)Bs) + (wave & 1) * 4096;
#pragma unroll
        for (int mt = 0; mt < 4; mt++)
#pragma unroll
            for (int nt = 0; nt < 4; nt++) {
                int dcol = nt * 16 + l15;
#pragma unroll
                for (int r = 0; r < 4; r++) {
                    int row = mt * 16 + quad * 4 + r;   // s within quadrant
                    int chunk = (row >> 3) ^ (dcol & 7);
                    T[dcol * 64 + chunk * 8 + (row & 7)] = (_Float16)acc[mt][nt][r];
                }
            }
        int h = (n0 - 4096) >> 7;
        int b = m0 >> 11;
        int sbase = (m0 & (SEQ - 1)) + wr * 64;
#pragma unroll
        for (int pass = 0; pass < 8; pass++) {
            int dl = pass * 8 + (lane >> 3);
            int sc = lane & 7;
            int chunk = sc ^ (dl & 7);
            u32x4 val = *(const u32x4*)(T + dl * 64 + chunk * 8);
            int d = wc * 64 + dl;
            *(u32x4*)(vt + ((size_t)((b * NH + h) * HD + d)) * SEQ + sbase + sc * 8) = val;
        }
        return;
    }

#pragma unroll
    for (int nt = 0; nt < 4; nt++) {
        int col = n0 + wc * 64 + nt * 16 + l15;
        float theta = 0.f;
        if (MODE == 1)
            theta = __expf(-((float)((col & 127) & ~1) * (1.0f / (float)HD)) * 9.210340371976184f);
#pragma unroll
        for (int mt = 0; mt < 4; mt++)
#pragma unroll
            for (int r = 0; r < 4; r++) {
                int row = m0 + wr * 64 + mt * 16 + quad * 4 + r;
                float val = acc[mt][nt][r];
                if (MODE == 1) {
                    float part = __shfl_xor(val, 1);
                    int s = row & (SEQ - 1);
                    float sn, cs;
                    __sincosf((float)s * theta, &sn, &cs);
                    val = (l15 & 1) ? val * cs + part * sn : val * cs - part * sn;
                }
                storeC_helper(C, (size_t)row * N + col, val);
            }
    }
}

// ---------------- flash attention (causal) ----------------
// r8 restructure: ONE block per (bh, qt) — 256 thr = 4 waves, full key range,
// no group split, no LDS merge. Grid (16,32) = 512 blocks; LDS 64KB -> 2
// independent blocks/CU at uncorrelated phases (block A's softmax VALU overlaps
// block B's MFMA; barriers couple only 4 waves). Longest blocks dispatched
// first (qt = 15 - blockIdx.x) to hide the qt-imbalance tail.
// S^T = K·Q^T so P exits in B-operand layout for 16x16x16 f16 PV.
__global__ __launch_bounds__(256, 2) void flash_kernel(const __hip_bfloat16* __restrict__ qkv,
                                                       const _Float16* __restrict__ vt,
                                                       __hip_bfloat16* __restrict__ attn) {
    __shared__ __align__(16) __hip_bfloat16 Ks[2][64 * 128];   // 32KB
    __shared__ __align__(16) _Float16 Vts[2][128 * 64];        // 32KB
    int tid  = threadIdx.x;
    int lane = tid & 63;
    int wl   = tid >> 6;          // wave 0..3
    int quad = lane >> 4;
    int l15  = lane & 15;
    int qt = 15 - blockIdx.x;     // longest first
    int bh = blockIdx.y;
    int b  = bh >> 4;
    int h  = bh & 15;
    size_t row0 = (size_t)b * SEQ;
    const _Float16* vbase = vt + (size_t)bh * HD * SEQ;
    const float scale = 0.08838834764831845f;
    const float NEG = -1e30f;

    auto stage = [&](int buf, int kt) {
#pragma unroll
        for (int c = 0; c < 4; c++) {
            int br = (wl * 4 + c) * 4;
            int r  = br + (lane >> 4);
            int cc = (lane & 15) ^ (r & 15);
            gload16(qkv + (row0 + kt * 64 + r) * (size_t)QKVN + DIM + h * HD + cc * 8,
                    &Ks[buf][br * 128]);
        }
#pragma unroll
        for (int c = 0; c < 4; c++) {
            int br = (wl * 4 + c) * 8;
            int r  = br + (lane >> 3);
            int cc = (lane & 7) ^ ((r >> 1) & 7);
            gload16(vbase + (size_t)r * SEQ + kt * 64 + cc * 8, &Vts[buf][br * 64]);
        }
    };

    int ntiles = 2 * (qt + 1);    // 64-key tiles covering keys 0..(qt+1)*128-1

    short8 qf[2][4];
#pragma unroll
    for (int mt = 0; mt < 2; mt++) {
        int qrow = qt * 128 + wl * 32 + mt * 16 + l15;
        const __hip_bfloat16* qptr = qkv + (row0 + qrow) * (size_t)QKVN + h * HD + quad * 8;
#pragma unroll
        for (int c = 0; c < 4; c++) qf[mt][c] = *(const short8*)(qptr + c * 32);
    }
    f32x4 o[2][8] = {};
    float m_[2] = {NEG, NEG}, l_[2] = {0.f, 0.f};

    stage(0, 0);

    for (int i = 0; i < ntiles; i++) {
        __syncthreads();
        if (i + 1 < ntiles) stage((i + 1) & 1, i + 1);
        const __hip_bfloat16* ks = Ks[i & 1];
        const _Float16* vts = Vts[i & 1];

        f32x4 s[2][4] = {};
#pragma unroll
        for (int ktile = 0; ktile < 4; ktile++) {
            int R = ktile * 16 + l15;
#pragma unroll
            for (int c = 0; c < 4; c++) {
                int phys = (c * 4 + quad) ^ (R & 15);
                short8 kf = *(const short8*)(ks + R * 128 + phys * 8);
                s[0][ktile] = __builtin_amdgcn_mfma_f32_16x16x32_bf16(kf, qf[0][c], s[0][ktile], 0, 0, 0);
                s[1][ktile] = __builtin_amdgcn_mfma_f32_16x16x32_bf16(kf, qf[1][c], s[1][ktile], 0, 0, 0);
            }
        }
        bool diag = (i >= 2 * qt);
        float alpha[2];
#pragma unroll
        for (int mt = 0; mt < 2; mt++) {
            int q = qt * 128 + wl * 32 + mt * 16 + l15;
#pragma unroll
            for (int ktile = 0; ktile < 4; ktile++)
#pragma unroll
                for (int r = 0; r < 4; r++) {
                    float v = s[mt][ktile][r] * scale;
                    if (diag) {
                        int key = i * 64 + ktile * 16 + quad * 4 + r;
                        if (key > q) v = NEG;
                    }
                    s[mt][ktile][r] = v;
                }
            float v = s[mt][0][0];
#pragma unroll
            for (int ktile = 0; ktile < 4; ktile++)
#pragma unroll
                for (int r = 0; r < 4; r++) v = fmaxf(v, s[mt][ktile][r]);
            v = fmaxf(v, __shfl_xor(v, 16));
            v = fmaxf(v, __shfl_xor(v, 32));
            float mnew = fmaxf(m_[mt], v);
            alpha[mt] = __expf(m_[mt] - mnew);
            m_[mt] = mnew;
            float sum = 0.f;
#pragma unroll
            for (int ktile = 0; ktile < 4; ktile++)
#pragma unroll
                for (int r = 0; r < 4; r++) {
                    float p = __expf(s[mt][ktile][r] - mnew);
                    s[mt][ktile][r] = p;
                    sum += p;
                }
            sum += __shfl_xor(sum, 16);
            sum += __shfl_xor(sum, 32);
            l_[mt] = l_[mt] * alpha[mt] + sum;
#pragma unroll
            for (int dt = 0; dt < 8; dt++) o[mt][dt] *= alpha[mt];
        }
        half4 pk[2][4];
#pragma unroll
        for (int mt = 0; mt < 2; mt++)
#pragma unroll
            for (int kc = 0; kc < 4; kc++)
#pragma unroll
                for (int r = 0; r < 4; r++) pk[mt][kc][r] = (_Float16)s[mt][kc][r];
#pragma unroll
        for (int kc = 0; kc < 4; kc++)
#pragma unroll
            for (int dt = 0; dt < 8; dt++) {
                int d = dt * 16 + l15;
                int c4 = ((kc * 4 + quad) ^ (d & 14));
                half4 vf = *(const half4*)(vts + d * 64 + c4 * 4);
                o[0][dt] = __builtin_amdgcn_mfma_f32_16x16x16f16(vf, pk[0][kc], o[0][dt], 0, 0, 0);
                o[1][dt] = __builtin_amdgcn_mfma_f32_16x16x16f16(vf, pk[1][kc], o[1][dt], 0, 0, 0);
            }
    }

    // ---- epilogue: scale by 1/l, transpose via LDS (reuse Ks), store bf16 ----
    __syncthreads();   // all waves done reading Ks/Vts
    __hip_bfloat16* tw = (__hip_bfloat16*)&Ks[0][0] + wl * 4096;
#pragma unroll
    for (int mt = 0; mt < 2; mt++) {
        float linv = 1.0f / l_[mt];
#pragma unroll
        for (int dt = 0; dt < 8; dt++) {
            int q32 = mt * 16 + l15;
            int c4 = dt * 4 + quad;
            int phys = c4 ^ ((q32 & 7) << 2);
            union { unsigned short u[4]; uint2 dw; } pkb;
#pragma unroll
            for (int r = 0; r < 4; r++) pkb.u[r] = f2bf(o[mt][dt][r] * linv);
            *(uint2*)(tw + q32 * 128 + phys * 4) = pkb.dw;
        }
    }
#pragma unroll
    for (int pass = 0; pass < 8; pass++) {
        int q32 = pass * 4 + (lane >> 4);
        int p = l15;
        int phys = (p * 2) ^ ((q32 & 7) << 2);
        u32x4 val = *(const u32x4*)(tw + q32 * 128 + phys * 4);
        int qg = qt * 128 + wl * 32 + q32;
        *(u32x4*)(attn + (row0 + qg) * (size_t)DIM + h * HD + p * 8) = val;
    }
}

extern "C" void kernel_launch(void* const* d_in, const int* in_sizes, int n_in,
                              void* d_out, int out_size, void* d_ws, size_t ws_size,
                              hipStream_t stream) {
    const float* x  = (const float*)d_in[0];
    const float* wq = (const float*)d_in[2];
    const float* wk = (const float*)d_in[3];
    const float* wv = (const float*)d_in[4];
    const float* wo = (const float*)d_in[5];
    float* out = (float*)d_out;

    char* ws = (char*)d_ws;
    __hip_bfloat16* xb    = (__hip_bfloat16*)(ws);                 // 4096x2048 (16MB)
    __hip_bfloat16* attn  = (__hip_bfloat16*)(ws);                 // reuses xb after QKV GEMM
    __hip_bfloat16* wqkvb = (__hip_bfloat16*)(ws + 16777216ull);   // 6144x2048 (24MB)
    __hip_bfloat16* wob   = (__hip_bfloat16*)(ws + 41943040ull);   // 2048x2048 (8MB)
    __hip_bfloat16* qkv   = (__hip_bfloat16*)(ws + 50331648ull);   // 4096x6144 (48MB; V cols unused)
    _Float16*       vtg   = (_Float16*)(ws + 100663296ull);        // 32x128x2048 f16 (16MB)

    const int nv = (BATCH * SEQ * DIM + 4 * DIM * DIM) / 4;
    cast_all<<<nv / 256, 256, 0, stream>>>(x, wq, wk, wv, wo, xb, wqkvb, wob);

    // QKV = xb @ wqkvb^T with fused RoPE (Q,K) + V-transpose epilogue
    gemm_bt<1, __hip_bfloat16><<<dim3(QKVN / 128, (BATCH * SEQ) / 128), 256, 0, stream>>>(
        xb, wqkvb, qkv, vtg, BATCH * SEQ, QKVN, DIM);

    // flash: one block per (bh, qt); longest blocks first
    flash_kernel<<<dim3(16, BATCH * NH), 256, 0, stream>>>(qkv, vtg, attn);

    // out = attn @ wo^T : M=4096, N=2048, K=2048 (fp32 out)
    gemm_bt<0, float><<<dim3(DIM / 128, (BATCH * SEQ) / 128), 256, 0, stream>>>(
        attn, wob, out, nullptr, BATCH * SEQ, DIM, DIM);
}

// Round 10
// 406.980 us; speedup vs baseline: 1.0251x; 1.0251x over previous
//
#include <hip/hip_runtime.h>
#include <hip/hip_bf16.h>
#include <math.h>

#define DIM   2048
#define NH    16
#define HD    128
#define SEQ   2048
#define BATCH 2
#define QKVN  6144   // 3*DIM

typedef __attribute__((ext_vector_type(8))) short short8;
typedef __attribute__((ext_vector_type(4))) float f32x4;
typedef __attribute__((ext_vector_type(4))) unsigned int u32x4;
typedef __attribute__((ext_vector_type(4))) _Float16 half4;

static __device__ __forceinline__ unsigned short f2bf(float f) {
    __hip_bfloat16 h = __float2bfloat16(f);
    return *reinterpret_cast<unsigned short*>(&h);
}

// async global->LDS, 16B per lane; LDS dest = base + lane*16 (wave-uniform base)
static __device__ __forceinline__ void gload16(const void* g, void* l) {
    __builtin_amdgcn_global_load_lds(
        (const __attribute__((address_space(1))) void*)(g),
        (__attribute__((address_space(3))) void*)(l), 16, 0, 0);
}

__device__ __forceinline__ void storeC_helper(float* C, size_t idx, float v) { C[idx] = v; }
__device__ __forceinline__ void storeC_helper(__hip_bfloat16* C, size_t idx, float v) { C[idx] = __float2bfloat16(v); }

// ---------------- fused cast fp32 -> bf16 (x + 4 weights, one launch) ----------------
__global__ __launch_bounds__(256) void cast_all(const float* __restrict__ x,
                                                const float* __restrict__ wq,
                                                const float* __restrict__ wk,
                                                const float* __restrict__ wv,
                                                const float* __restrict__ wo,
                                                __hip_bfloat16* __restrict__ xb,
                                                __hip_bfloat16* __restrict__ wqkvb,
                                                __hip_bfloat16* __restrict__ wob) {
    const int VX = (BATCH * SEQ * DIM) / 4;
    const int VW = (DIM * DIM) / 4;
    int v = blockIdx.x * blockDim.x + threadIdx.x;
    const float* src; __hip_bfloat16* dst; int off;
    if (v < VX)               { src = x;  dst = xb;                            off = v; }
    else if (v < VX + VW)     { src = wq; dst = wqkvb;                         off = v - VX; }
    else if (v < VX + 2 * VW) { src = wk; dst = wqkvb + (size_t)DIM * DIM;     off = v - VX - VW; }
    else if (v < VX + 3 * VW) { src = wv; dst = wqkvb + 2ull * DIM * DIM;      off = v - VX - 2 * VW; }
    else                      { src = wo; dst = wob;                           off = v - VX - 3 * VW; }
    float4 f = *(const float4*)(src + (size_t)off * 4);
    union { unsigned short u[4]; uint2 d; } pk;
    pk.u[0] = f2bf(f.x); pk.u[1] = f2bf(f.y); pk.u[2] = f2bf(f.z); pk.u[3] = f2bf(f.w);
    *(uint2*)(dst + (size_t)off * 4) = pk.d;
}

// ---------------- bf16 GEMM, C[m,n] = sum_k A[m,k]*B[n,k] ----------------
// MODE 0: plain store to C.  MODE 1: QKV-fused — n<4096: RoPE + bf16 store;
// n>=4096: V tile transposed via LDS, stored f16 to vt[bh][d][s].
template <int MODE, typename OutT>
__global__ __launch_bounds__(256) void gemm_bt(const __hip_bfloat16* __restrict__ A,
                                               const __hip_bfloat16* __restrict__ B,
                                               OutT* __restrict__ C,
                                               _Float16* __restrict__ vt,
                                               int M, int N, int K) {
    constexpr int BK = 64;
    __shared__ __align__(16) __hip_bfloat16 As[128 * BK];
    __shared__ __align__(16) __hip_bfloat16 Bs[128 * BK];
    int tid  = threadIdx.x;
    int lane = tid & 63;
    int wave = tid >> 6;
    int quad = lane >> 4;
    int l15  = lane & 15;
    int wr   = wave >> 1, wc = wave & 1;
    int m0 = blockIdx.y * 128;
    int n0 = blockIdx.x * 128;
    f32x4 acc[4][4] = {};

    for (int k0 = 0; k0 < K; k0 += BK) {
        __syncthreads();
#pragma unroll
        for (int c = 0; c < 4; c++) {
            int br = (wave * 4 + c) * 8;
            int r  = br + (lane >> 3);
            int cc = (lane & 7) ^ (r & 7);
            gload16(A + (size_t)(m0 + r) * K + k0 + cc * 8, As + br * 64);
            gload16(B + (size_t)(n0 + r) * K + k0 + cc * 8, Bs + br * 64);
        }
        __syncthreads();
#pragma unroll
        for (int kk = 0; kk < BK; kk += 32) {
            short8 af[4], bf4[4];
#pragma unroll
            for (int t = 0; t < 4; t++) {
                int Ra = wr * 64 + t * 16 + l15;
                int pa = ((kk >> 3) + quad) ^ (Ra & 7);
                af[t] = *(const short8*)(As + Ra * 64 + pa * 8);
                int Rb = wc * 64 + t * 16 + l15;
                int pb = ((kk >> 3) + quad) ^ (Rb & 7);
                bf4[t] = *(const short8*)(Bs + Rb * 64 + pb * 8);
            }
#pragma unroll
            for (int mt = 0; mt < 4; mt++)
#pragma unroll
                for (int nt = 0; nt < 4; nt++)
                    acc[mt][nt] = __builtin_amdgcn_mfma_f32_16x16x32_bf16(af[mt], bf4[nt], acc[mt][nt], 0, 0, 0);
        }
    }

    if (MODE == 1 && n0 >= 4096) {
        // ---- V branch: transpose 64x64 wave quadrant via LDS, store f16 ----
        __syncthreads();   // all waves done reading As/Bs
        _Float16* T = ((wave < 2) ? (_Float16*)As : (_Float16*)Bs) + (wave & 1) * 4096;
#pragma unroll
        for (int mt = 0; mt < 4; mt++)
#pragma unroll
            for (int nt = 0; nt < 4; nt++) {
                int dcol = nt * 16 + l15;
#pragma unroll
                for (int r = 0; r < 4; r++) {
                    int row = mt * 16 + quad * 4 + r;   // s within quadrant
                    int chunk = (row >> 3) ^ (dcol & 7);
                    T[dcol * 64 + chunk * 8 + (row & 7)] = (_Float16)acc[mt][nt][r];
                }
            }
        int h = (n0 - 4096) >> 7;
        int b = m0 >> 11;
        int sbase = (m0 & (SEQ - 1)) + wr * 64;
#pragma unroll
        for (int pass = 0; pass < 8; pass++) {
            int dl = pass * 8 + (lane >> 3);
            int sc = lane & 7;
            int chunk = sc ^ (dl & 7);
            u32x4 val = *(const u32x4*)(T + dl * 64 + chunk * 8);
            int d = wc * 64 + dl;
            *(u32x4*)(vt + ((size_t)((b * NH + h) * HD + d)) * SEQ + sbase + sc * 8) = val;
        }
        return;
    }

#pragma unroll
    for (int nt = 0; nt < 4; nt++) {
        int col = n0 + wc * 64 + nt * 16 + l15;
        float theta = 0.f;
        if (MODE == 1)
            theta = __expf(-((float)((col & 127) & ~1) * (1.0f / (float)HD)) * 9.210340371976184f);
#pragma unroll
        for (int mt = 0; mt < 4; mt++)
#pragma unroll
            for (int r = 0; r < 4; r++) {
                int row = m0 + wr * 64 + mt * 16 + quad * 4 + r;
                float val = acc[mt][nt][r];
                if (MODE == 1) {
                    float part = __shfl_xor(val, 1);
                    int s = row & (SEQ - 1);
                    float sn, cs;
                    __sincosf((float)s * theta, &sn, &cs);
                    val = (l15 & 1) ? val * cs + part * sn : val * cs - part * sn;
                }
                storeC_helper(C, (size_t)row * N + col, val);
            }
    }
}

// ---------------- flash attention (causal) ----------------
// r10: 256 thr = 4 waves per block; block owns a 64-q-row HALF (rh) of a qt
// tile, FULL key range (no group split, no LDS merge). Balance restored inside
// the block: each block runs BOTH segments qt=pairi and qt=15-pairi -> every
// block = exactly 34 key-tiles regardless of scheduler assignment (r9's
// failure was per-CU (qt,qt) pairing). LDS 64KB -> 2 blocks/CU co-resident,
// decorrelated phases (block A softmax VALU overlaps block B MFMA). Per-wave
// state ~92 VGPR (one 16-row set) — no spill at 2 waves/EU.
// S^T = K·Q^T so P exits in B-operand layout for 16x16x16 f16 PV.
__global__ __launch_bounds__(256) void flash_kernel(const __hip_bfloat16* __restrict__ qkv,
                                                    const _Float16* __restrict__ vt,
                                                    __hip_bfloat16* __restrict__ attn) {
    __shared__ __align__(16) __hip_bfloat16 Ks[2][64 * 128];   // 32KB
    __shared__ __align__(16) _Float16 Vts[2][128 * 64];        // 32KB
    int tid  = threadIdx.x;
    int lane = tid & 63;
    int wl   = tid >> 6;          // wave 0..3
    int quad = lane >> 4;
    int l15  = lane & 15;
    int pairi = blockIdx.x & 7;
    int rh    = blockIdx.x >> 3;  // q-row half of the 128-row tile
    int bh = blockIdx.y;
    int b  = bh >> 4;
    int h  = bh & 15;
    size_t row0 = (size_t)b * SEQ;
    const _Float16* vbase = vt + (size_t)bh * HD * SEQ;
    const float scale = 0.08838834764831845f;
    const float NEG = -1e30f;

    auto stage = [&](int buf, int kt) {
#pragma unroll
        for (int c = 0; c < 4; c++) {
            int br = (wl * 4 + c) * 4;
            int r  = br + (lane >> 4);
            int cc = (lane & 15) ^ (r & 15);
            gload16(qkv + (row0 + kt * 64 + r) * (size_t)QKVN + DIM + h * HD + cc * 8,
                    &Ks[buf][br * 128]);
        }
#pragma unroll
        for (int c = 0; c < 4; c++) {
            int br = (wl * 4 + c) * 8;
            int r  = br + (lane >> 3);
            int cc = (lane & 7) ^ ((r >> 1) & 7);
            gload16(vbase + (size_t)r * SEQ + kt * 64 + cc * 8, &Vts[buf][br * 64]);
        }
    };

    for (int seg = 0; seg < 2; seg++) {
        int qt = seg ? (15 - pairi) : pairi;
        int ntiles = 2 * (qt + 1);

        short8 qf[4];
        {
            int qrow = qt * 128 + rh * 64 + wl * 16 + l15;
            const __hip_bfloat16* qptr = qkv + (row0 + qrow) * (size_t)QKVN + h * HD + quad * 8;
#pragma unroll
            for (int c = 0; c < 4; c++) qf[c] = *(const short8*)(qptr + c * 32);
        }
        f32x4 o[8] = {};
        float m_ = NEG, l_ = 0.f;

        stage(0, 0);

        for (int i = 0; i < ntiles; i++) {
            __syncthreads();
            if (i + 1 < ntiles) stage((i + 1) & 1, i + 1);
            const __hip_bfloat16* ks = Ks[i & 1];
            const _Float16* vts = Vts[i & 1];

            f32x4 s[4] = {};
#pragma unroll
            for (int ktile = 0; ktile < 4; ktile++) {
                int R = ktile * 16 + l15;
#pragma unroll
                for (int c = 0; c < 4; c++) {
                    int phys = (c * 4 + quad) ^ (R & 15);
                    short8 kf = *(const short8*)(ks + R * 128 + phys * 8);
                    s[ktile] = __builtin_amdgcn_mfma_f32_16x16x32_bf16(kf, qf[c], s[ktile], 0, 0, 0);
                }
            }
            bool diag = (i >= 2 * qt);
            int q = qt * 128 + rh * 64 + wl * 16 + l15;
#pragma unroll
            for (int ktile = 0; ktile < 4; ktile++)
#pragma unroll
                for (int r = 0; r < 4; r++) {
                    float v = s[ktile][r] * scale;
                    if (diag) {
                        int key = i * 64 + ktile * 16 + quad * 4 + r;
                        if (key > q) v = NEG;
                    }
                    s[ktile][r] = v;
                }
            float v = s[0][0];
#pragma unroll
            for (int ktile = 0; ktile < 4; ktile++)
#pragma unroll
                for (int r = 0; r < 4; r++) v = fmaxf(v, s[ktile][r]);
            v = fmaxf(v, __shfl_xor(v, 16));
            v = fmaxf(v, __shfl_xor(v, 32));
            float mnew = fmaxf(m_, v);
            float alpha = __expf(m_ - mnew);
            m_ = mnew;
            float sum = 0.f;
#pragma unroll
            for (int ktile = 0; ktile < 4; ktile++)
#pragma unroll
                for (int r = 0; r < 4; r++) {
                    float p = __expf(s[ktile][r] - mnew);
                    s[ktile][r] = p;
                    sum += p;
                }
            sum += __shfl_xor(sum, 16);
            sum += __shfl_xor(sum, 32);
            l_ = l_ * alpha + sum;
#pragma unroll
            for (int dt = 0; dt < 8; dt++) o[dt] *= alpha;

            half4 pk[4];
#pragma unroll
            for (int kc = 0; kc < 4; kc++)
#pragma unroll
                for (int r = 0; r < 4; r++) pk[kc][r] = (_Float16)s[kc][r];
#pragma unroll
            for (int kc = 0; kc < 4; kc++)
#pragma unroll
                for (int dt = 0; dt < 8; dt++) {
                    int d = dt * 16 + l15;
                    int c4 = ((kc * 4 + quad) ^ (d & 14));
                    half4 vf = *(const half4*)(vts + d * 64 + c4 * 4);
                    o[dt] = __builtin_amdgcn_mfma_f32_16x16x16f16(vf, pk[kc], o[dt], 0, 0, 0);
                }
        }

        // ---- epilogue: scale by 1/l, transpose via LDS (reuse Ks[0]), store bf16 ----
        __syncthreads();   // all waves done reading Ks/Vts this segment
        __hip_bfloat16* tw = (__hip_bfloat16*)&Ks[0][0] + wl * 2048;
        {
            float linv = 1.0f / l_;
#pragma unroll
            for (int dt = 0; dt < 8; dt++) {
                int q16 = l15;
                int c4 = dt * 4 + quad;
                int phys = c4 ^ ((q16 & 7) << 2);
                union { unsigned short u[4]; uint2 dw; } pkb;
#pragma unroll
                for (int r = 0; r < 4; r++) pkb.u[r] = f2bf(o[dt][r] * linv);
                *(uint2*)(tw + q16 * 128 + phys * 4) = pkb.dw;
            }
        }
#pragma unroll
        for (int pass = 0; pass < 4; pass++) {
            int q16 = pass * 4 + (lane >> 4);
            int p = l15;
            int phys = (p * 2) ^ ((q16 & 7) << 2);
            u32x4 val = *(const u32x4*)(tw + q16 * 128 + phys * 4);
            int qg = qt * 128 + rh * 64 + wl * 16 + q16;
            *(u32x4*)(attn + (row0 + qg) * (size_t)DIM + h * HD + p * 8) = val;
        }
        __syncthreads();   // tw reads done before next segment's stage overwrites Ks[0]
    }
}

extern "C" void kernel_launch(void* const* d_in, const int* in_sizes, int n_in,
                              void* d_out, int out_size, void* d_ws, size_t ws_size,
                              hipStream_t stream) {
    const float* x  = (const float*)d_in[0];
    const float* wq = (const float*)d_in[2];
    const float* wk = (const float*)d_in[3];
    const float* wv = (const float*)d_in[4];
    const float* wo = (const float*)d_in[5];
    float* out = (float*)d_out;

    char* ws = (char*)d_ws;
    __hip_bfloat16* xb    = (__hip_bfloat16*)(ws);                 // 4096x2048 (16MB)
    __hip_bfloat16* attn  = (__hip_bfloat16*)(ws);                 // reuses xb after QKV GEMM
    __hip_bfloat16* wqkvb = (__hip_bfloat16*)(ws + 16777216ull);   // 6144x2048 (24MB)
    __hip_bfloat16* wob   = (__hip_bfloat16*)(ws + 41943040ull);   // 2048x2048 (8MB)
    __hip_bfloat16* qkv   = (__hip_bfloat16*)(ws + 50331648ull);   // 4096x6144 (48MB; V cols unused)
    _Float16*       vtg   = (_Float16*)(ws + 100663296ull);        // 32x128x2048 f16 (16MB)

    const int nv = (BATCH * SEQ * DIM + 4 * DIM * DIM) / 4;
    cast_all<<<nv / 256, 256, 0, stream>>>(x, wq, wk, wv, wo, xb, wqkvb, wob);

    // QKV = xb @ wqkvb^T with fused RoPE (Q,K) + V-transpose epilogue
    gemm_bt<1, __hip_bfloat16><<<dim3(QKVN / 128, (BATCH * SEQ) / 128), 256, 0, stream>>>(
        xb, wqkvb, qkv, vtg, BATCH * SEQ, QKVN, DIM);

    // flash: 512 balanced blocks — (pairi, rh) x bh; both segments per block
    flash_kernel<<<dim3(16, BATCH * NH), 256, 0, stream>>>(qkv, vtg, attn);

    // out = attn @ wo^T : M=4096, N=2048, K=2048 (fp32 out)
    gemm_bt<0, float><<<dim3(DIM / 128, (BATCH * SEQ) / 128), 256, 0, stream>>>(
        attn, wob, out, nullptr, BATCH * SEQ, DIM, DIM);
}